// Round 14
// baseline (233.600 us; speedup 1.0000x reference)
//
#include <hip/hip_runtime.h>
#include <stdint.h>

#define NBOX 1024
#define UNK  0xFFFFFFFFFFFFFFFFull

typedef unsigned long long u64;
typedef unsigned int u32;
typedef unsigned short u16;
typedef unsigned char u8;

// ---------- bit-exact IoU (matches numpy f32 op-for-op; _rn blocks FMA contraction) ----------
__device__ __forceinline__ float iou_pair(const float4 lb, float larea,
                                          const float4 pb, float parea) {
    float ix1 = fmaxf(lb.x, pb.x);
    float iy1 = fmaxf(lb.y, pb.y);
    float ix2 = fminf(lb.z, pb.z);
    float iy2 = fminf(lb.w, pb.w);
    float w = fmaxf(__fsub_rn(ix2, ix1), 0.0f);
    float h = fmaxf(__fsub_rn(iy2, iy1), 0.0f);
    float inter = __fmul_rn(w, h);
    float denom = __fsub_rn(__fadd_rn(larea, parea), inter);
    return inter / denom;
}

__device__ __forceinline__ u64 umax64(u64 a, u64 b) { return a > b ? a : b; }
__device__ __forceinline__ u64 umin64(u64 a, u64 b) { return a < b ? a : b; }

// ---------- 64-lane u64 max butterfly via DPP; result valid in lane 63 ----------
__device__ __forceinline__ u64 dpp_max64(u64 v) {
    unsigned lo, hi; u64 o;
#define DPP_STEP(CTRL) \
    lo = (unsigned)__builtin_amdgcn_update_dpp(0, (int)(unsigned)(v & 0xffffffffull), CTRL, 0xf, 0xf, true); \
    hi = (unsigned)__builtin_amdgcn_update_dpp(0, (int)(unsigned)(v >> 32),           CTRL, 0xf, 0xf, true); \
    o = (((u64)hi) << 32) | lo; \
    if (o > v) v = o;
    DPP_STEP(0x111) DPP_STEP(0x112) DPP_STEP(0x114)
    DPP_STEP(0x118) DPP_STEP(0x142) DPP_STEP(0x143)
#undef DPP_STEP
    return v;
}

// ---------- 64-lane top-2 reduce (distinct packed keys); result valid in lane 63 ----------
__device__ __forceinline__ void dpp_top2(u64 &a1, u64 &a2) {
    unsigned lo, hi; u64 b1, b2, min1;
#define T2STEP(CTRL) \
    lo = (unsigned)__builtin_amdgcn_update_dpp(0, (int)(unsigned)(a1 & 0xffffffffull), CTRL, 0xf, 0xf, true); \
    hi = (unsigned)__builtin_amdgcn_update_dpp(0, (int)(unsigned)(a1 >> 32),           CTRL, 0xf, 0xf, true); \
    b1 = (((u64)hi) << 32) | lo; \
    lo = (unsigned)__builtin_amdgcn_update_dpp(0, (int)(unsigned)(a2 & 0xffffffffull), CTRL, 0xf, 0xf, true); \
    hi = (unsigned)__builtin_amdgcn_update_dpp(0, (int)(unsigned)(a2 >> 32),           CTRL, 0xf, 0xf, true); \
    b2 = (((u64)hi) << 32) | lo; \
    min1 = (b1 == a1) ? 0ull : umin64(a1, b1); \
    a1 = umax64(a1, b1); \
    a2 = umax64(umax64(a2, b2), min1);
    T2STEP(0x111) T2STEP(0x112) T2STEP(0x114) T2STEP(0x118) T2STEP(0x142) T2STEP(0x143)
#undef T2STEP
}

__device__ __forceinline__ u64 readlane64(u64 v, int l) {
    unsigned lo = (unsigned)__builtin_amdgcn_readlane((int)(unsigned)(v & 0xffffffffull), l);
    unsigned hi = (unsigned)__builtin_amdgcn_readlane((int)(unsigned)(v >> 32), l);
    return (((u64)hi) << 32) | lo;
}
__device__ __forceinline__ u32 readlane32(u32 v, int l) {
    return (u32)__builtin_amdgcn_readlane((int)v, l);
}

// overlap-free 16-lane-row shift step for u64 top-2 (distinct keys, no dedupe needed)
#define SHR_T2_STEP(a1, a2, CTRL) { \
    unsigned _lo, _hi; u64 _b1, _b2, _mn; \
    _lo = (unsigned)__builtin_amdgcn_update_dpp(0, (int)(unsigned)((a1) & 0xffffffffull), CTRL, 0xf, 0xf, true); \
    _hi = (unsigned)__builtin_amdgcn_update_dpp(0, (int)(unsigned)((a1) >> 32),           CTRL, 0xf, 0xf, true); \
    _b1 = (((u64)_hi) << 32) | _lo; \
    _lo = (unsigned)__builtin_amdgcn_update_dpp(0, (int)(unsigned)((a2) & 0xffffffffull), CTRL, 0xf, 0xf, true); \
    _hi = (unsigned)__builtin_amdgcn_update_dpp(0, (int)(unsigned)((a2) >> 32),           CTRL, 0xf, 0xf, true); \
    _b2 = (((u64)_hi) << 32) | _lo; \
    _mn = umin64((a1), _b1); \
    (a1) = umax64((a1), _b1); \
    (a2) = umax64(umax64((a2), _b2), _mn); }

// overlap-free 16-lane-row shift step for u32 (v1,v2); equal values correctly flag v2==v1
#define SHR_V2_STEP(v1, v2, CTRL) { \
    u32 _s1 = (u32)__builtin_amdgcn_update_dpp(0, (int)(v1), CTRL, 0xf, 0xf, true); \
    u32 _s2 = (u32)__builtin_amdgcn_update_dpp(0, (int)(v2), CTRL, 0xf, 0xf, true); \
    u32 _mn = (v1) < _s1 ? (v1) : _s1; \
    (v1) = (v1) > _s1 ? (v1) : _s1; \
    u32 _m2 = (v2) > _s2 ? (v2) : _s2; \
    (v2) = _m2 > _mn ? _m2 : _mn; }

// =====================================================================================
// Init A (1024 blocks): JM row b + top-2 row keys for label b.
// =====================================================================================
__global__ void __launch_bounds__(64) jm_init(const float* __restrict__ labels,
                                              const float* __restrict__ preds,
                                              float* __restrict__ JM,      // may be null
                                              u64* __restrict__ rkey_ws,
                                              u64* __restrict__ rkey2_ws) {
    const int b = blockIdx.x;
    const int lane = threadIdx.x;
    float4 lb = ((const float4*)labels)[b];
    float la = __fmul_rn(__fsub_rn(lb.z, lb.x), __fsub_rn(lb.w, lb.y));
    u64 a1 = 0, a2 = 0;
    #pragma unroll
    for (int m = 0; m < 4; ++m) {
        float4 v;
        float* vv = (float*)&v;
        #pragma unroll
        for (int k = 0; k < 4; ++k) {
            int c = 4 * lane + 256 * m + k;
            float4 pb = ((const float4*)preds)[c];
            float pa = __fmul_rn(__fsub_rn(pb.z, pb.x), __fsub_rn(pb.w, pb.y));
            vv[k] = iou_pair(lb, la, pb, pa);
        }
        if (JM) ((float4*)JM)[b * 256 + lane + 64 * m] = v;
        #pragma unroll
        for (int k = 0; k < 4; ++k) {
            int c = 4 * lane + 256 * m + k;
            u64 p = ((u64)__float_as_uint(vv[k]) << 10) | (unsigned)c;
            a2 = umax64(a2, umin64(a1, p));
            a1 = umax64(a1, p);
        }
    }
    dpp_top2(a1, a2);
    if (lane == 63) {
        if ((a1 >> 10) == 0ull) { rkey_ws[b] = 0ull; rkey2_ws[b] = 0ull; }
        else { rkey_ws[b] = a1; rkey2_ws[b] = (a2 >> 10) ? a2 : 0ull; }
    }
}

// =====================================================================================
// Init B (1024 blocks): col bound cub + coalesced JMT row (JMT[c][L] = IoU(L, c)).
// =====================================================================================
__global__ void __launch_bounds__(64) init_colmax(const float* __restrict__ labels,
                                                  const float* __restrict__ preds,
                                                  float* __restrict__ JMT,   // may be null
                                                  u64* __restrict__ cub_ws) {
    const int c = blockIdx.x;
    const int lane = threadIdx.x;
    float4 pc = ((const float4*)preds)[c];
    float pa = __fmul_rn(__fsub_rn(pc.z, pc.x), __fsub_rn(pc.w, pc.y));
    u64 best = 0; u32 v1 = 0, v2 = 0;
    #pragma unroll
    for (int j = 0; j < 16; ++j) {
        int L = lane + (j << 6);
        float4 lb = ((const float4*)labels)[L];
        float la = __fmul_rn(__fsub_rn(lb.z, lb.x), __fsub_rn(lb.w, lb.y));
        float v = iou_pair(lb, la, pc, pa);
        if (JMT) JMT[(size_t)c * NBOX + L] = v;
        u32 vb = __float_as_uint(v);
        if (vb >= v1) { v2 = v1; v1 = vb; } else { v2 = (vb > v2) ? vb : v2; }
        best = umax64(best, ((u64)vb << 10) | (unsigned)L);
    }
    best = dpp_max64(best);
    u64 bm = readlane64(best, 63);
    u32 V = (u32)(bm >> 10);
    u64 b1 = __ballot(v1 == V);
    u64 b2 = __ballot(v2 == V);
    bool tie = (__popcll(b1) >= 2) || (b2 != 0ull);
    if (lane == 63)
        cub_ws[c] = V ? (((u64)V << 32) | (tie ? (1ull << 16) : 0ull) | (bm & 1023ull))
                      : 0ull;
}

// =====================================================================================
// Main: 16-wave parallel greedy; 2 barriers/round (P1 check/scan/commit | P2 masks/
//   promote/scan/push). pos removed (provably never affects commits); chase once at end.
// =====================================================================================
__global__ void __launch_bounds__(1024, 1)
rounds_kernel(const float* __restrict__ preds,
              const float* __restrict__ labels,
              const float* __restrict__ JM,      // may be null
              const float* __restrict__ JMT,     // may be null
              const u64* __restrict__ rkey_ws,   // may be null (then all ws null)
              const u64* __restrict__ rkey2_ws,
              const u64* __restrict__ cub_ws,
              float* __restrict__ out) {
    __shared__ float4 pred4s[NBOX];
    __shared__ float4 lab4s[NBOX];
    __shared__ float  parea_s[NBOX];
    __shared__ float  larea_s[NBOX];
    __shared__ u64    rkey[NBOX];
    __shared__ u64    rkey2[NBOX];
    __shared__ u64    cub[NBOX];
    __shared__ u64    colbest[NBOX];   // suitor: (val<<10)|label
    __shared__ u16    dest_s[NBOX];
    __shared__ u16    perm_s[NBOX];
    __shared__ u8     seenc[NBOX];
    __shared__ u8     lockedl[NBOX];
    __shared__ u32    seenw[32];
    __shared__ u32    lockedw[32];
    __shared__ int    ncom[2];
    __shared__ float  fpart[16];

    const int t    = (int)threadIdx.x;
    const int lane = t & 63;
    const int wid  = t >> 6;

    {
        float4 p = ((const float4*)preds)[t];
        float4 L = ((const float4*)labels)[t];
        pred4s[t] = p;
        lab4s[t]  = L;
        parea_s[t] = __fmul_rn(__fsub_rn(p.z, p.x), __fsub_rn(p.w, p.y));
        larea_s[t] = __fmul_rn(__fsub_rn(L.z, L.x), __fsub_rn(L.w, L.y));
        perm_s[t] = (u16)t; dest_s[t] = 0;
        seenc[t] = 0; lockedl[t] = 0;
        rkey[t]  = rkey_ws  ? rkey_ws[t]  : 0ull;
        rkey2[t] = rkey2_ws ? rkey2_ws[t] : UNK;
        cub[t]   = cub_ws   ? cub_ws[t]   : 0ull;
        colbest[t] = 0ull;
        if (t < 32) { seenw[t] = 0u; lockedw[t] = 0u; }
        if (t < 2) ncom[t] = 0;
    }
    __syncthreads();

    u32 myseen = 0;    // bit (m<<2)|k : col 4*lane+256m+k consumed
    u32 mylocked = 0;  // bit (m<<2)|k : label 4*lane+256m+k locked
    int par = 0;       // round parity for ncom

    // ---- pairwise exact top-2 row scan; uniform results (val<<10)|col packed ----
    auto scan_row2 = [&](int La, int Lb, bool hb,
                         u64 &r1a, u64 &r2a, u64 &r1b, u64 &r2b) {
        u32 av1 = 0, ac1 = 0, av2 = 0, ac2 = 0;
        u32 bv1 = 0, bc1 = 0, bv2 = 0, bc2 = 0;
        if (JM) {
            const float4* A4 = (const float4*)(JM + (size_t)La * NBOX);
            const float4* B4 = (const float4*)(JM + (size_t)Lb * NBOX);
            #pragma unroll
            for (int m = 0; m < 4; ++m) {
                float4 fa = A4[lane + 64 * m];
                float4 fb = B4[lane + 64 * m];
                const float* qa = (const float*)&fa;
                const float* qb = (const float*)&fb;
                #pragma unroll
                for (int k = 0; k < 4; ++k) {
                    u32 cc = (u32)(4 * lane + 256 * m + k);
                    bool msk = (myseen >> ((m << 2) | k)) & 1u;
                    u32 va = __float_as_uint(qa[k]);
                    u32 vb = __float_as_uint(qb[k]);
                    if (!msk && va) {
                        if (va >= av1) { av2 = av1; ac2 = ac1; av1 = va; ac1 = cc; }
                        else if (va >= av2) { av2 = va; ac2 = cc; }
                    }
                    if (!msk && vb) {
                        if (vb >= bv1) { bv2 = bv1; bc2 = bc1; bv1 = vb; bc1 = cc; }
                        else if (vb >= bv2) { bv2 = vb; bc2 = cc; }
                    }
                }
            }
        } else {
            float4 lba = lab4s[La]; float laa = larea_s[La];
            float4 lbb = lab4s[Lb]; float lbb_a = larea_s[Lb];
            #pragma unroll
            for (int m = 0; m < 4; ++m) {
                #pragma unroll
                for (int k = 0; k < 4; ++k) {
                    u32 cc = (u32)(4 * lane + 256 * m + k);
                    bool msk = (myseen >> ((m << 2) | k)) & 1u;
                    u32 va = __float_as_uint(iou_pair(lba, laa, pred4s[cc], parea_s[cc]));
                    u32 vb = __float_as_uint(iou_pair(lbb, lbb_a, pred4s[cc], parea_s[cc]));
                    if (!msk && va) {
                        if (va >= av1) { av2 = av1; ac2 = ac1; av1 = va; ac1 = cc; }
                        else if (va >= av2) { av2 = va; ac2 = cc; }
                    }
                    if (!msk && vb) {
                        if (vb >= bv1) { bv2 = bv1; bc2 = bc1; bv1 = vb; bc1 = cc; }
                        else if (vb >= bv2) { bv2 = vb; bc2 = cc; }
                    }
                }
            }
        }
        u64 a1 = ((u64)av1 << 10) | ac1, a2 = ((u64)av2 << 10) | ac2;
        u64 b1 = ((u64)bv1 << 10) | bc1, b2 = ((u64)bv2 << 10) | bc2;
        SHR_T2_STEP(a1, a2, 0x111) SHR_T2_STEP(b1, b2, 0x111)
        SHR_T2_STEP(a1, a2, 0x112) SHR_T2_STEP(b1, b2, 0x112)
        SHR_T2_STEP(a1, a2, 0x114) SHR_T2_STEP(b1, b2, 0x114)
        SHR_T2_STEP(a1, a2, 0x118) SHR_T2_STEP(b1, b2, 0x118)
        {
            u64 p1 = readlane64(a1, 15), p2 = readlane64(a2, 15);
            u64 q1 = readlane64(a1, 31), q2 = readlane64(a2, 31);
            u64 s1 = readlane64(a1, 47), s2 = readlane64(a2, 47);
            u64 w1 = readlane64(a1, 63), w2 = readlane64(a2, 63);
            u64 mn = umin64(p1, q1); p1 = umax64(p1, q1); p2 = umax64(umax64(p2, q2), mn);
            mn = umin64(s1, w1); s1 = umax64(s1, w1); s2 = umax64(umax64(s2, w2), mn);
            mn = umin64(p1, s1); p1 = umax64(p1, s1); p2 = umax64(umax64(p2, s2), mn);
            r1a = p1; r2a = p2;
        }
        if (hb) {
            u64 p1 = readlane64(b1, 15), p2 = readlane64(b2, 15);
            u64 q1 = readlane64(b1, 31), q2 = readlane64(b2, 31);
            u64 s1 = readlane64(b1, 47), s2 = readlane64(b2, 47);
            u64 w1 = readlane64(b1, 63), w2 = readlane64(b2, 63);
            u64 mn = umin64(p1, q1); p1 = umax64(p1, q1); p2 = umax64(umax64(p2, q2), mn);
            mn = umin64(s1, w1); s1 = umax64(s1, w1); s2 = umax64(umax64(s2, w2), mn);
            mn = umin64(p1, s1); p1 = umax64(p1, s1); p2 = umax64(umax64(p2, s2), mn);
            r1b = p1; r2b = p2;
        } else { r1b = 0; r2b = 0; }
    };

    // store top-2 row scan result (uniform in); lane 0 writes
    auto store_rkey = [&](int L, u64 r1, u64 r2) {
        if (lane == 0) {
            if ((r1 >> 10) == 0ull) { rkey[L] = 0ull; rkey2[L] = 0ull; }
            else { rkey[L] = r1; rkey2[L] = (r2 >> 10) ? r2 : 0ull; }
        }
    };

    // exact col scan with tie detect (slow path); uniform result, pos-free
    auto scan_col_exact = [&](int c) -> u64 {
        u64 best = 0; u32 v1 = 0, v2 = 0;
        if (JMT) {
            const float4* col4 = (const float4*)(JMT + (size_t)c * NBOX);
            #pragma unroll
            for (int m = 0; m < 4; ++m) {
                float4 f = col4[lane + 64 * m];
                const float* ff = (const float*)&f;
                #pragma unroll
                for (int k = 0; k < 4; ++k) {
                    int L = 4 * lane + 256 * m + k;
                    u32 vb = __float_as_uint(ff[k]);
                    if ((mylocked >> ((m << 2) | k)) & 1u) vb = 0;
                    if (vb >= v1) { v2 = v1; v1 = vb; } else { v2 = (vb > v2) ? vb : v2; }
                    best = umax64(best, ((u64)vb << 10) | (unsigned)L);
                }
            }
        } else {
            float4 pc = pred4s[c];
            float  pa = parea_s[c];
            #pragma unroll
            for (int m = 0; m < 4; ++m) {
                #pragma unroll
                for (int k = 0; k < 4; ++k) {
                    int L = 4 * lane + 256 * m + k;
                    float v = iou_pair(lab4s[L], larea_s[L], pc, pa);
                    u32 vb = __float_as_uint(v);
                    if ((mylocked >> ((m << 2) | k)) & 1u) vb = 0;
                    if (vb >= v1) { v2 = v1; v1 = vb; } else { v2 = (vb > v2) ? vb : v2; }
                    best = umax64(best, ((u64)vb << 10) | (unsigned)L);
                }
            }
        }
        best = dpp_max64(best);
        u64 bm = readlane64(best, 63);
        u32 V = (u32)(bm >> 10);
        u64 b1 = __ballot(v1 == V);
        u64 b2 = __ballot(v2 == V);
        bool tie = (__popcll(b1) >= 2) || (b2 != 0ull);
        return V ? (((u64)V << 32) | (tie ? (1ull << 16) : 0ull) | (bm & 1023ull)) : 0ull;
    };

    // pairwise fast col scan; returns cub-format or UNK (tie -> caller runs exact)
    auto scan_col2 = [&](int ca, int cb, bool hb, u64 &oa, u64 &ob) {
        u32 av1 = 0, av2 = 0, al1 = 0;
        u32 bv1 = 0, bv2 = 0, bl1 = 0;
        if (JMT) {
            const float4* A4 = (const float4*)(JMT + (size_t)ca * NBOX);
            const float4* B4 = (const float4*)(JMT + (size_t)cb * NBOX);
            #pragma unroll
            for (int m = 0; m < 4; ++m) {
                float4 fa = A4[lane + 64 * m];
                float4 fb = B4[lane + 64 * m];
                const float* qa = (const float*)&fa;
                const float* qb = (const float*)&fb;
                #pragma unroll
                for (int k = 0; k < 4; ++k) {
                    u32 L = (u32)(4 * lane + 256 * m + k);
                    bool msk = (mylocked >> ((m << 2) | k)) & 1u;
                    u32 va = msk ? 0u : __float_as_uint(qa[k]);
                    u32 vb = msk ? 0u : __float_as_uint(qb[k]);
                    if (va > av1) { av2 = av1; av1 = va; al1 = L; }
                    else av2 = (va > av2) ? va : av2;
                    if (vb > bv1) { bv2 = bv1; bv1 = vb; bl1 = L; }
                    else bv2 = (vb > bv2) ? vb : bv2;
                }
            }
        } else {
            float4 pca = pred4s[ca]; float paa = parea_s[ca];
            float4 pcb = pred4s[cb]; float pab = parea_s[cb];
            #pragma unroll
            for (int m = 0; m < 4; ++m) {
                #pragma unroll
                for (int k = 0; k < 4; ++k) {
                    u32 L = (u32)(4 * lane + 256 * m + k);
                    bool msk = (mylocked >> ((m << 2) | k)) & 1u;
                    u32 va = msk ? 0u : __float_as_uint(iou_pair(lab4s[L], larea_s[L], pca, paa));
                    u32 vb = msk ? 0u : __float_as_uint(iou_pair(lab4s[L], larea_s[L], pcb, pab));
                    if (va > av1) { av2 = av1; av1 = va; al1 = L; }
                    else av2 = (va > av2) ? va : av2;
                    if (vb > bv1) { bv2 = bv1; bv1 = vb; bl1 = L; }
                    else bv2 = (vb > bv2) ? vb : bv2;
                }
            }
        }
        u32 sva = av1, sla = al1;      // pre-merge lane copies
        u32 svb = bv1, slb = bl1;
        SHR_V2_STEP(av1, av2, 0x111) SHR_V2_STEP(bv1, bv2, 0x111)
        SHR_V2_STEP(av1, av2, 0x112) SHR_V2_STEP(bv1, bv2, 0x112)
        SHR_V2_STEP(av1, av2, 0x114) SHR_V2_STEP(bv1, bv2, 0x114)
        SHR_V2_STEP(av1, av2, 0x118) SHR_V2_STEP(bv1, bv2, 0x118)
        u32 Va, V2a, Vb, V2b;
        {
            u32 p1 = readlane32(av1, 15), p2 = readlane32(av2, 15);
            u32 q1 = readlane32(av1, 31), q2 = readlane32(av2, 31);
            u32 s1 = readlane32(av1, 47), s2 = readlane32(av2, 47);
            u32 w1 = readlane32(av1, 63), w2 = readlane32(av2, 63);
            u32 mn = p1 < q1 ? p1 : q1; p1 = p1 > q1 ? p1 : q1;
            p2 = p2 > q2 ? p2 : q2; p2 = p2 > mn ? p2 : mn;
            mn = s1 < w1 ? s1 : w1; s1 = s1 > w1 ? s1 : w1;
            s2 = s2 > w2 ? s2 : w2; s2 = s2 > mn ? s2 : mn;
            mn = p1 < s1 ? p1 : s1; p1 = p1 > s1 ? p1 : s1;
            p2 = p2 > s2 ? p2 : s2; p2 = p2 > mn ? p2 : mn;
            Va = p1; V2a = p2;
        }
        {
            u32 p1 = readlane32(bv1, 15), p2 = readlane32(bv2, 15);
            u32 q1 = readlane32(bv1, 31), q2 = readlane32(bv2, 31);
            u32 s1 = readlane32(bv1, 47), s2 = readlane32(bv2, 47);
            u32 w1 = readlane32(bv1, 63), w2 = readlane32(bv2, 63);
            u32 mn = p1 < q1 ? p1 : q1; p1 = p1 > q1 ? p1 : q1;
            p2 = p2 > q2 ? p2 : q2; p2 = p2 > mn ? p2 : mn;
            mn = s1 < w1 ? s1 : w1; s1 = s1 > w1 ? s1 : w1;
            s2 = s2 > w2 ? s2 : w2; s2 = s2 > mn ? s2 : mn;
            mn = p1 < s1 ? p1 : s1; p1 = p1 > s1 ? p1 : s1;
            p2 = p2 > s2 ? p2 : s2; p2 = p2 > mn ? p2 : mn;
            Vb = p1; V2b = p2;
        }
        if (Va == 0) oa = 0ull;
        else if (V2a == Va) oa = UNK;                    // tie -> exact rescan
        else {
            u64 ball = __ballot(sva == Va);
            int wl = (int)__ffsll(ball) - 1;
            u32 lbl = readlane32(sla, wl);
            oa = ((u64)Va << 32) | lbl;
        }
        if (!hb) { ob = 0ull; return; }
        if (Vb == 0) ob = 0ull;
        else if (V2b == Vb) ob = UNK;
        else {
            u64 ball = __ballot(svb == Vb);
            int wl = (int)__ffsll(ball) - 1;
            u32 lbl = readlane32(slb, wl);
            ob = ((u64)Vb << 32) | lbl;
        }
    };

    // commit (lane 0 only); sb_ = register-copied suitor entry for col c
    auto try_commit = [&](int c, u64 cbv, u64 sb_) {
        if (sb_ && cbv && !((cbv >> 16) & 1ull) &&
            (u32)(cbv & 1023ull) == (u32)(sb_ & 1023ull)) {
            int L = (int)(sb_ & 1023ull);
            seenc[c] = 1; lockedl[L] = 1; rkey[L] = 0ull;
            dest_s[L] = (u16)c; perm_s[c] = (u16)L;
            atomicOr(&seenw[c >> 5], 1u << (c & 31));
            atomicOr(&lockedw[L >> 5], 1u << (L & 31));
            atomicAdd(&ncom[par], 1);
        }
    };

    if (!rkey_ws) {   // in-kernel init fallback
        for (int L = 2 * wid; L < NBOX; L += 32) {
            u64 r1a, r2a, r1b, r2b;
            scan_row2(L, L + 1, true, r1a, r2a, r1b, r2b);
            store_rkey(L, r1a, r2a);
            store_rkey(L + 1, r1b, r2b);
        }
        for (int c = 2 * wid; c < NBOX; c += 32) {
            u64 oa, ob;
            scan_col2(c, c + 1, true, oa, ob);
            if (oa == UNK) oa = scan_col_exact(c);
            if (ob == UNK) ob = scan_col_exact(c + 1);
            if (lane == 0) { cub[c] = oa; cub[c + 1] = ob; }
        }
        __syncthreads();
    }

    // ---- initial suitor push ----
    {
        u64 k = rkey[t];
        if (k) atomicMax((unsigned long long*)&colbest[k & 1023ull],
                         ((k >> 10) << 10) | (u64)(unsigned)t);
    }
    __syncthreads();

    for (int round = 0; round < 2048; ++round) {
        par = round & 1;

        // ---- P1: read+clear suitors, fast check, paired scans, immediate commits ----
        {
            u64 sb = colbest[t];
            colbest[t] = 0ull;
            bool need = false;
            if (sb) {
                u32 sval = (u32)(sb >> 10);
                u32 slab = (u32)(sb & 1023ull);
                u64 cb = cub[t];
                u32 cval = (u32)(cb >> 32);
                u32 clab = (u32)(cb & 1023ull);
                bool ctie = (cb >> 16) & 1ull;
                if (lockedl[clab] || ctie || (sval == cval && slab != clab)) {
                    need = true;
                } else if (slab == clab) {        // dominant pair: commit now
                    int c = t, L = (int)slab;
                    seenc[c] = 1; lockedl[L] = 1; rkey[L] = 0ull;
                    dest_s[L] = (u16)c; perm_s[c] = (u16)L;
                    atomicOr(&seenw[c >> 5], 1u << (c & 31));
                    atomicOr(&lockedw[L >> 5], 1u << (L & 31));
                    atomicAdd(&ncom[par], 1);
                }
            }
            u64 bal = __ballot(need);
            while (bal) {
                int l0 = (int)__ffsll(bal) - 1; bal &= bal - 1;
                int l1 = l0; bool hb = false;
                if (bal) { l1 = (int)__ffsll(bal) - 1; bal &= bal - 1; hb = true; }
                int c0 = (wid << 6) | l0, c1 = (wid << 6) | l1;
                u64 sb0 = readlane64(sb, l0);
                u64 sb1 = hb ? readlane64(sb, l1) : 0ull;
                u64 o0, o1;
                scan_col2(c0, c1, hb, o0, o1);
                if (o0 == UNK) o0 = scan_col_exact(c0);
                if (hb && o1 == UNK) o1 = scan_col_exact(c1);
                if (lane == 0) {
                    cub[c0] = o0; try_commit(c0, o0, sb0);
                    if (hb) { cub[c1] = o1; try_commit(c1, o1, sb1); }
                }
            }
        }
        __syncthreads();

        // ---- P2: termination, mask rebuild, promote + row scans, push ----
        const int cnt = ncom[par];
        if (t == 0) ncom[par ^ 1] = 0;
        if (cnt == 0) break;                      // no commits -> perm final
        {
            u32 ms = 0, ml = 0;
            #pragma unroll
            for (int m = 0; m < 4; ++m) {
                u32 ws_ = seenw[(lane >> 3) + (m << 3)];
                u32 wl  = lockedw[(lane >> 3) + (m << 3)];
                u32 sh  = (lane & 7) << 2;
                ms |= ((ws_ >> sh) & 0xFu) << (m << 2);
                ml |= ((wl  >> sh) & 0xFu) << (m << 2);
            }
            myseen = ms; mylocked = ml;
        }
        {
            bool needrow = false;
            u64 k = rkey[t];
            if (k && seenc[k & 1023ull]) {
                u64 k2 = rkey2[t];
                if (k2 != UNK) {
                    rkey[t] = k2;                 // exact promotion (or dead if 0)
                    rkey2[t] = UNK;
                    if (k2 && seenc[k2 & 1023ull]) needrow = true;
                } else {
                    needrow = true;
                }
            }
            u64 bal = __ballot(needrow);
            while (bal) {
                int l0 = (int)__ffsll(bal) - 1; bal &= bal - 1;
                int l1 = l0; bool hb = false;
                if (bal) { l1 = (int)__ffsll(bal) - 1; bal &= bal - 1; hb = true; }
                int r0 = (wid << 6) | l0, r1_ = (wid << 6) | l1;
                u64 r1a, r2a, r1b, r2b;
                scan_row2(r0, r1_, hb, r1a, r2a, r1b, r2b);
                store_rkey(r0, r1a, r2a);
                if (hb) store_rkey(r1_, r1b, r2b);
            }
        }
        {
            u64 k = rkey[t];                      // final for this round (wave-local order)
            if (k) atomicMax((unsigned long long*)&colbest[k & 1023ull],
                             ((k >> 10) << 10) | (u64)(unsigned)t);
        }
        __syncthreads();
    }

    // ---- one-time displacement chase for open rows ----
    if (!seenc[t]) {
        int l = t;
        while (lockedl[l]) l = (int)dest_s[l];
        perm_s[t] = (u16)l;
    }
    __syncthreads();

    // ---- loss = mean |labels[perm] - predictions| ----
    {
        float4 lb = lab4s[perm_s[t]];
        float4 pb = pred4s[t];
        float sum = fabsf(lb.x - pb.x) + fabsf(lb.y - pb.y) +
                    fabsf(lb.z - pb.z) + fabsf(lb.w - pb.w);
        for (int off = 32; off > 0; off >>= 1) sum += __shfl_xor(sum, off, 64);
        if (lane == 0) fpart[wid] = sum;
        __syncthreads();
        if (t == 0) {
            float s = 0.0f;
            for (int w = 0; w < 16; ++w) s += fpart[w];
            out[0] = s * (1.0f / 4096.0f);
        }
    }
}

extern "C" void kernel_launch(void* const* d_in, const int* in_sizes, int n_in,
                              void* d_out, int out_size, void* d_ws, size_t ws_size,
                              hipStream_t stream) {
    const float* preds  = (const float*)d_in[0];   // predictions [1024,4]
    const float* labels = (const float*)d_in[1];   // labels      [1024,4]
    float* out = (float*)d_out;

    const size_t jm_b   = (size_t)NBOX * NBOX * sizeof(float);   // 4 MB
    const size_t keys_b = 3 * NBOX * sizeof(u64);                // 24 KB

    float *JM = nullptr, *JMT = nullptr;
    u64 *rk = nullptr, *rk2 = nullptr, *cb = nullptr;
    char* w = (char*)d_ws;

    if (d_ws && ws_size >= 2 * jm_b + keys_b) {
        JM  = (float*)w;
        JMT = (float*)(w + jm_b);
        rk  = (u64*)(w + 2 * jm_b); rk2 = rk + NBOX; cb = rk2 + NBOX;
    } else if (d_ws && ws_size >= jm_b + keys_b) {
        JM  = (float*)w;
        rk  = (u64*)(w + jm_b); rk2 = rk + NBOX; cb = rk2 + NBOX;
    } else if (d_ws && ws_size >= keys_b) {
        rk  = (u64*)w; rk2 = rk + NBOX; cb = rk2 + NBOX;
    }

    if (rk) {
        jm_init<<<NBOX, 64, 0, stream>>>(labels, preds, JM, rk, rk2);
        init_colmax<<<NBOX, 64, 0, stream>>>(labels, preds, JMT, cb);
    }
    rounds_kernel<<<1, 1024, 0, stream>>>(preds, labels, JM, JMT, rk, rk2, cb, out);
}

// Round 15
// 221.810 us; speedup vs baseline: 1.0532x; 1.0532x over previous
//
#include <hip/hip_runtime.h>
#include <stdint.h>

#define NBOX 1024

typedef unsigned long long u64;
typedef unsigned int u32;
typedef unsigned short u16;
typedef unsigned char u8;

// ---------- bit-exact IoU (matches numpy f32 op-for-op; _rn blocks FMA contraction) ----------
__device__ __forceinline__ float iou_pair(const float4 lb, float larea,
                                          const float4 pb, float parea) {
    float ix1 = fmaxf(lb.x, pb.x);
    float iy1 = fmaxf(lb.y, pb.y);
    float ix2 = fminf(lb.z, pb.z);
    float iy2 = fminf(lb.w, pb.w);
    float w = fmaxf(__fsub_rn(ix2, ix1), 0.0f);
    float h = fmaxf(__fsub_rn(iy2, iy1), 0.0f);
    float inter = __fmul_rn(w, h);
    float denom = __fsub_rn(__fadd_rn(larea, parea), inter);
    return inter / denom;
}

__device__ __forceinline__ u64 umax64(u64 a, u64 b) { return a > b ? a : b; }

// ---------- 64-lane u64 max butterfly via DPP; result valid in lane 63 ----------
__device__ __forceinline__ u64 dpp_max64(u64 v) {
    unsigned lo, hi; u64 o;
#define DPP_STEP(CTRL) \
    lo = (unsigned)__builtin_amdgcn_update_dpp(0, (int)(unsigned)(v & 0xffffffffull), CTRL, 0xf, 0xf, true); \
    hi = (unsigned)__builtin_amdgcn_update_dpp(0, (int)(unsigned)(v >> 32),           CTRL, 0xf, 0xf, true); \
    o = (((u64)hi) << 32) | lo; \
    if (o > v) v = o;
    DPP_STEP(0x111) DPP_STEP(0x112) DPP_STEP(0x114)
    DPP_STEP(0x118) DPP_STEP(0x142) DPP_STEP(0x143)
#undef DPP_STEP
    return v;
}

__device__ __forceinline__ u64 readlane64(u64 v, int l) {
    unsigned lo = (unsigned)__builtin_amdgcn_readlane((int)(unsigned)(v & 0xffffffffull), l);
    unsigned hi = (unsigned)__builtin_amdgcn_readlane((int)(unsigned)(v >> 32), l);
    return (((u64)hi) << 32) | lo;
}

// =====================================================================================
// Init A (1024 blocks): rowlist[b][0..7] = sorted top-8 (valbits<<10)|col, desc (val,col).
//   Zero entries pad when fewer than 8 positive cols exist.
// =====================================================================================
__global__ void __launch_bounds__(64) init_rowlist(const float* __restrict__ labels,
                                                   const float* __restrict__ preds,
                                                   u64* __restrict__ rowlist) {
    const int b = blockIdx.x;
    const int lane = threadIdx.x;
    float4 lb = ((const float4*)labels)[b];
    float la = __fmul_rn(__fsub_rn(lb.z, lb.x), __fsub_rn(lb.w, lb.y));
    u32 vb[16];
    #pragma unroll
    for (int j = 0; j < 16; ++j) {
        int c = lane + (j << 6);
        float4 pb = ((const float4*)preds)[c];
        float pa = __fmul_rn(__fsub_rn(pb.z, pb.x), __fsub_rn(pb.w, pb.y));
        vb[j] = __float_as_uint(iou_pair(lb, la, pb, pa));
    }
    u32 used = 0;
    for (int it = 0; it < 8; ++it) {
        u64 best = 0;
        #pragma unroll
        for (int j = 0; j < 16; ++j) {
            if (!((used >> j) & 1u)) {
                u64 p = ((u64)vb[j] << 10) | (u32)(lane + (j << 6));
                best = umax64(best, p);
            }
        }
        best = dpp_max64(best);
        u64 bm = readlane64(best, 63);
        if ((bm >> 10) == 0ull) bm = 0;
        if (lane == 0) rowlist[(b << 3) + it] = bm;
        if (bm && (int)(bm & 63) == lane) used |= 1u << ((bm >> 6) & 15);
    }
}

// =====================================================================================
// Init B (1024 blocks): collist[c][0..7] = sorted top-8 (valbits<<10)|label, desc.
// =====================================================================================
__global__ void __launch_bounds__(64) init_collist(const float* __restrict__ labels,
                                                   const float* __restrict__ preds,
                                                   u64* __restrict__ collist) {
    const int c = blockIdx.x;
    const int lane = threadIdx.x;
    float4 pc = ((const float4*)preds)[c];
    float pa = __fmul_rn(__fsub_rn(pc.z, pc.x), __fsub_rn(pc.w, pc.y));
    u32 vb[16];
    #pragma unroll
    for (int j = 0; j < 16; ++j) {
        int L = lane + (j << 6);
        float4 lb = ((const float4*)labels)[L];
        float la = __fmul_rn(__fsub_rn(lb.z, lb.x), __fsub_rn(lb.w, lb.y));
        vb[j] = __float_as_uint(iou_pair(lb, la, pc, pa));
    }
    u32 used = 0;
    for (int it = 0; it < 8; ++it) {
        u64 best = 0;
        #pragma unroll
        for (int j = 0; j < 16; ++j) {
            if (!((used >> j) & 1u)) {
                u64 p = ((u64)vb[j] << 10) | (u32)(lane + (j << 6));
                best = umax64(best, p);
            }
        }
        best = dpp_max64(best);
        u64 bm = readlane64(best, 63);
        if ((bm >> 10) == 0ull) bm = 0;
        if (lane == 0) collist[(c << 3) + it] = bm;
        if (bm && (int)(bm & 63) == lane) used |= 1u << ((bm >> 6) & 15);
    }
}

// =====================================================================================
// Main: 16-wave parallel greedy; per-thread top-8 list walks replace full scans.
//   Exact fallbacks (compute-from-LDS scans) on list exhaustion / tie boundary.
// =====================================================================================
__global__ void __launch_bounds__(1024, 1)
rounds_kernel(const float* __restrict__ preds,
              const float* __restrict__ labels,
              const u64* __restrict__ rowlist,   // may be null (fallback-only mode)
              const u64* __restrict__ collist,   // may be null
              float* __restrict__ out) {
    __shared__ float4 pred4s[NBOX];
    __shared__ float4 lab4s[NBOX];
    __shared__ float  parea_s[NBOX];
    __shared__ float  larea_s[NBOX];
    __shared__ u64    rkey[NBOX];      // (val<<10)|col ; 0 = dead/locked
    __shared__ u64    colbest[NBOX];   // suitor: (val<<10)|label
    __shared__ u16    dest_s[NBOX];
    __shared__ u16    perm_s[NBOX];
    __shared__ u8     seenc[NBOX];
    __shared__ u8     lockedl[NBOX];
    __shared__ u32    seenw[32];
    __shared__ u32    lockedw[32];
    __shared__ int    ncom[2];
    __shared__ float  fpart[16];

    const int t    = (int)threadIdx.x;
    const int lane = t & 63;
    const int wid  = t >> 6;

    {
        float4 p = ((const float4*)preds)[t];
        float4 L = ((const float4*)labels)[t];
        pred4s[t] = p;
        lab4s[t]  = L;
        parea_s[t] = __fmul_rn(__fsub_rn(p.z, p.x), __fsub_rn(p.w, p.y));
        larea_s[t] = __fmul_rn(__fsub_rn(L.z, L.x), __fsub_rn(L.w, L.y));
        perm_s[t] = (u16)t; dest_s[t] = 0;
        seenc[t] = 0; lockedl[t] = 0;
        rkey[t] = rowlist ? rowlist[t << 3] : 0ull;
        colbest[t] = 0ull;
        if (t < 32) { seenw[t] = 0u; lockedw[t] = 0u; }
        if (t < 2) ncom[t] = 0;
    }
    __syncthreads();

    u32 myseen = 0;    // bit (m<<2)|k : col 4*lane+256m+k consumed (fallback scans)
    u32 mylocked = 0;  // bit (m<<2)|k : label 4*lane+256m+k locked
    int rptr = rowlist ? 0 : 8;   // row-list cursor (8 = exhausted -> full rescans)
    int cptr = collist ? 0 : 8;   // col-list cursor
    int par = 0;

    auto rebuild_seen = [&]() {
        u32 ms = 0;
        #pragma unroll
        for (int m = 0; m < 4; ++m) {
            u32 w_ = seenw[(lane >> 3) + (m << 3)];
            ms |= ((w_ >> ((lane & 7) << 2)) & 0xFu) << (m << 2);
        }
        myseen = ms;
    };
    auto rebuild_locked = [&]() {
        u32 ml = 0;
        #pragma unroll
        for (int m = 0; m < 4; ++m) {
            u32 w_ = lockedw[(lane >> 3) + (m << 3)];
            ml |= ((w_ >> ((lane & 7) << 2)) & 0xFu) << (m << 2);
        }
        mylocked = ml;
    };

    // exact row scan over unseen cols (tie -> larger col); uniform row; uses myseen
    auto scan_row_exact = [&](int row) -> u64 {
        float4 lbx = lab4s[row];
        float la = larea_s[row];
        u64 best = 0;
        #pragma unroll
        for (int m = 0; m < 4; ++m) {
            #pragma unroll
            for (int k = 0; k < 4; ++k) {
                int cc = 4 * lane + 256 * m + k;
                float v = iou_pair(lbx, la, pred4s[cc], parea_s[cc]);
                u64 p = ((u64)__float_as_uint(v) << 10) | (unsigned)cc;
                if ((myseen >> ((m << 2) | k)) & 1u) p = 0;
                best = umax64(best, p);
            }
        }
        best = dpp_max64(best);
        u64 bm = readlane64(best, 63);
        return (bm >> 10) ? bm : 0ull;
    };

    // exact col scan over unlocked labels + tie flag; uniform col; uses mylocked
    auto scan_col_exact = [&](int c) -> u64 {
        float4 pc = pred4s[c];
        float  pa = parea_s[c];
        u64 best = 0; u32 v1 = 0, v2 = 0;
        #pragma unroll
        for (int m = 0; m < 4; ++m) {
            #pragma unroll
            for (int k = 0; k < 4; ++k) {
                int L = 4 * lane + 256 * m + k;
                float v = iou_pair(lab4s[L], larea_s[L], pc, pa);
                u32 vbb = __float_as_uint(v);
                if ((mylocked >> ((m << 2) | k)) & 1u) vbb = 0;
                if (vbb >= v1) { v2 = v1; v1 = vbb; } else { v2 = (vbb > v2) ? vbb : v2; }
                best = umax64(best, ((u64)vbb << 10) | (unsigned)L);
            }
        }
        best = dpp_max64(best);
        u64 bm = readlane64(best, 63);
        u32 V = (u32)(bm >> 10);
        if (!V) return 0ull;
        u64 b1 = __ballot(v1 == V);
        u64 b2 = __ballot(v2 == V);
        bool tie = (__popcll(b1) >= 2) || (b2 != 0ull);
        return ((u64)V << 32) | (tie ? (1ull << 16) : 0ull) | (bm & 1023ull);
    };

    auto do_commit = [&](int c, int L) {
        seenc[c] = 1; lockedl[L] = 1; rkey[L] = 0ull;
        dest_s[L] = (u16)c; perm_s[c] = (u16)L;
        atomicOr(&seenw[c >> 5], 1u << (c & 31));
        atomicOr(&lockedw[L >> 5], 1u << (L & 31));
        atomicAdd(&ncom[par], 1);
    };

    if (!rowlist) {   // no-ws fallback init: exact row maxes (myseen == 0 here)
        for (int row = wid; row < NBOX; row += 16) {
            u64 r = scan_row_exact(row);
            if (lane == 0) rkey[row] = r;
        }
        __syncthreads();
    }

    // ---- initial suitor push ----
    {
        u64 k = rkey[t];
        if (k) atomicMax((unsigned long long*)&colbest[k & 1023ull],
                         ((k >> 10) << 10) | (u64)(unsigned)t);
    }
    __syncthreads();

    for (int round = 0; round < 4096; ++round) {
        par = round & 1;

        // ---- P1: per-col list walk -> commit / defer / exact fallback ----
        u64 sb = colbest[t];
        {
            colbest[t] = 0ull;
            bool needexact = false;
            if (sb) {
                if (cptr >= 8) {
                    needexact = true;
                } else {
                    u32 V = 0, lab1 = 0; bool dead = false;
                    int i = cptr;
                    for (; i < 8; ++i) {
                        u64 e = collist[(t << 3) + i];
                        u32 v = (u32)(e >> 10);
                        if (!v) { dead = true; break; }
                        u32 lb = (u32)(e & 1023ull);
                        if (!lockedl[lb]) { V = v; lab1 = lb; break; }
                    }
                    cptr = i;                     // skip permanently-locked prefix
                    if (!dead) {
                        if (i >= 8) {
                            needexact = true;     // exhausted: all 8 positive & locked
                        } else {
                            bool tie = false;
                            int j = i + 1;
                            for (; j < 8; ++j) {
                                u64 e2 = collist[(t << 3) + j];
                                u32 v2 = (u32)(e2 >> 10);
                                if (v2 != V) break;
                                if (!lockedl[e2 & 1023ull]) { tie = true; break; }
                            }
                            if (!tie && j >= 8) needexact = true;  // V == list[7].val boundary
                            if (!needexact && !tie) {
                                if ((u32)(sb & 1023ull) == lab1) do_commit(t, (int)lab1);
                            } // tie -> defer (matches prior ctie semantics)
                        }
                    }
                }
            }
            u64 bal = __ballot(needexact);
            if (bal) {
                rebuild_locked();
                while (bal) {
                    int l = (int)__ffsll(bal) - 1; bal &= bal - 1;
                    int c = (wid << 6) | l;
                    u64 o = scan_col_exact(c);
                    u64 sbl = readlane64(sb, l);
                    if (lane == 0) {
                        u32 Vx = (u32)(o >> 32);
                        if (Vx && !((o >> 16) & 1ull) &&
                            (u32)(o & 1023ull) == (u32)(sbl & 1023ull))
                            do_commit(c, (int)(o & 1023ull));
                    }
                }
            }
        }
        __syncthreads();

        // ---- P2: termination, per-row list promotion, fallback scans, push ----
        const int cnt = ncom[par];
        if (t == 0) ncom[par ^ 1] = 0;
        if (cnt == 0) break;                      // no commits -> perm final
        {
            bool needscan = false;
            u64 k = rkey[t];
            if (k && seenc[k & 1023ull]) {
                if (rptr >= 8) {
                    needscan = true;
                } else {
                    int i = rptr; u64 nk = 0;
                    for (; i < 8; ++i) {
                        u64 e = rowlist[(t << 3) + i];
                        if ((e >> 10) == 0ull) break;        // dead (zero-kill)
                        if (!seenc[e & 1023ull]) { nk = e; break; }
                    }
                    if (i < 8) { rkey[t] = nk; rptr = i; }   // promote (or dead if nk==0)
                    else { rptr = 8; needscan = true; }      // exhausted -> full rescans
                }
            }
            u64 bal = __ballot(needscan);
            if (bal) {
                rebuild_seen();
                while (bal) {
                    int l = (int)__ffsll(bal) - 1; bal &= bal - 1;
                    int row = (wid << 6) | l;
                    u64 r = scan_row_exact(row);
                    if (lane == 0) rkey[row] = r;
                }
            }
            u64 k2 = rkey[t];
            if (k2) atomicMax((unsigned long long*)&colbest[k2 & 1023ull],
                              ((k2 >> 10) << 10) | (u64)(unsigned)t);
        }
        __syncthreads();
    }

    // ---- one-time displacement chase for open rows ----
    if (!seenc[t]) {
        int l = t;
        while (lockedl[l]) l = (int)dest_s[l];
        perm_s[t] = (u16)l;
    }
    __syncthreads();

    // ---- loss = mean |labels[perm] - predictions| ----
    {
        float4 lb = lab4s[perm_s[t]];
        float4 pb = pred4s[t];
        float sum = fabsf(lb.x - pb.x) + fabsf(lb.y - pb.y) +
                    fabsf(lb.z - pb.z) + fabsf(lb.w - pb.w);
        for (int off = 32; off > 0; off >>= 1) sum += __shfl_xor(sum, off, 64);
        if (lane == 0) fpart[wid] = sum;
        __syncthreads();
        if (t == 0) {
            float s = 0.0f;
            for (int w = 0; w < 16; ++w) s += fpart[w];
            out[0] = s * (1.0f / 4096.0f);
        }
    }
}

extern "C" void kernel_launch(void* const* d_in, const int* in_sizes, int n_in,
                              void* d_out, int out_size, void* d_ws, size_t ws_size,
                              hipStream_t stream) {
    const float* preds  = (const float*)d_in[0];   // predictions [1024,4]
    const float* labels = (const float*)d_in[1];   // labels      [1024,4]
    float* out = (float*)d_out;

    const size_t list_b = (size_t)NBOX * 8 * sizeof(u64);   // 64 KB each
    if (d_ws && ws_size >= 2 * list_b) {
        u64* rl = (u64*)d_ws;
        u64* cl = rl + NBOX * 8;
        init_rowlist<<<NBOX, 64, 0, stream>>>(labels, preds, rl);
        init_collist<<<NBOX, 64, 0, stream>>>(labels, preds, cl);
        rounds_kernel<<<1, 1024, 0, stream>>>(preds, labels, rl, cl, out);
    } else {
        rounds_kernel<<<1, 1024, 0, stream>>>(preds, labels, nullptr, nullptr, out);
    }
}